// Round 1
// baseline (109.927 us; speedup 1.0000x reference)
//
#include <hip/hip_runtime.h>

#define C_CLS 19
#define NBINS 512
#define HW_SHIFT 19            // H*W = 512*1024 = 2^19
#define HW (1 << HW_SHIFT)
#define NPIX (4 * HW)          // B=4
#define IGNORE_LAB 255

// ---------------------------------------------------------------------------
// Kernel 1: softmax + per-(class,bin) histogram of err = |fg - p_c|.
// LDS histogram packs (count<<16)|fg_count per entry (max 4096 pixels/block).
// Flush: one u64 global atomic per nonempty entry: (count<<32)|fg.
// ---------------------------------------------------------------------------
__global__ __launch_bounds__(256) void lovasz_hist(
    const float* __restrict__ logits, const int* __restrict__ label,
    unsigned long long* __restrict__ g_hist)
{
    __shared__ unsigned hist[C_CLS * NBINS];
    for (int i = threadIdx.x; i < C_CLS * NBINS; i += blockDim.x) hist[i] = 0u;
    __syncthreads();

    const int npairs = NPIX / 2;
    const int stride = gridDim.x * blockDim.x;
    for (int pr = blockIdx.x * blockDim.x + threadIdx.x; pr < npairs; pr += stride) {
        const long long p = (long long)pr * 2;
        const int b  = (int)(p >> HW_SHIFT);
        const int hw = (int)(p & (HW - 1));
        const float* base = logits + ((long long)b * C_CLS << HW_SHIFT) + hw;

        float2 e[C_CLS];
        float mx = -3.0e38f, my = -3.0e38f;
        #pragma unroll
        for (int c = 0; c < C_CLS; ++c) {
            float2 v = *(const float2*)(base + ((long long)c << HW_SHIFT));
            e[c] = v;
            mx = fmaxf(mx, v.x);
            my = fmaxf(my, v.y);
        }
        float sx = 0.f, sy = 0.f;
        #pragma unroll
        for (int c = 0; c < C_CLS; ++c) {
            float ex = __expf(e[c].x - mx);
            float ey = __expf(e[c].y - my);
            e[c].x = ex; e[c].y = ey;
            sx += ex; sy += ey;
        }
        const float rx = 1.f / sx, ry = 1.f / sy;

        const int2 lab = *(const int2*)(label + p);
        const bool v0 = (lab.x != IGNORE_LAB);
        const bool v1 = (lab.y != IGNORE_LAB);

        #pragma unroll
        for (int c = 0; c < C_CLS; ++c) {
            if (v0) {
                const float pc = e[c].x * rx;
                const unsigned fg = (lab.x == c) ? 1u : 0u;
                const float err = fg ? (1.f - pc) : pc;
                int bin = (int)(err * (float)NBINS);
                bin = bin > (NBINS - 1) ? (NBINS - 1) : bin;
                atomicAdd(&hist[c * NBINS + bin], 0x10000u + fg);
            }
            if (v1) {
                const float pc = e[c].y * ry;
                const unsigned fg = (lab.y == c) ? 1u : 0u;
                const float err = fg ? (1.f - pc) : pc;
                int bin = (int)(err * (float)NBINS);
                bin = bin > (NBINS - 1) ? (NBINS - 1) : bin;
                atomicAdd(&hist[c * NBINS + bin], 0x10000u + fg);
            }
        }
    }
    __syncthreads();

    for (int i = threadIdx.x; i < C_CLS * NBINS; i += blockDim.x) {
        const unsigned v = hist[i];
        if (v) {
            const unsigned long long add =
                ((unsigned long long)(v >> 16) << 32) | (unsigned long long)(v & 0xFFFFu);
            atomicAdd(&g_hist[i], add);
        }
    }
}

// ---------------------------------------------------------------------------
// Kernel 2: per class (one wave each), scan bins in DESCENDING err order.
// jacc(T,F) = 1 - (gts-F)/(gts+T-F) at exact integer boundaries (fp64).
// loss += bin_center * (jacc_after - jacc_before); atomicAdd into out.
// ---------------------------------------------------------------------------
__global__ __launch_bounds__(64) void lovasz_finalize(
    const unsigned long long* __restrict__ g_hist, float* __restrict__ out)
{
    const int c = blockIdx.x;          // class
    const int lane = threadIdx.x;      // 0..63
    const int PER = NBINS / 64;        // 8 bins per lane

    unsigned n[8], f[8];
    unsigned nl = 0, fl = 0;
    #pragma unroll
    for (int k = 0; k < PER; ++k) {
        const int s = lane * PER + k;          // sequence position (desc err)
        const int bin = NBINS - 1 - s;
        const unsigned long long h = g_hist[c * NBINS + bin];
        n[k] = (unsigned)(h >> 32);
        f[k] = (unsigned)(h & 0xFFFFFFFFull);
        nl += n[k]; fl += f[k];
    }

    // inclusive wave scan over lanes
    unsigned ni = nl, fi = fl;
    for (int off = 1; off < 64; off <<= 1) {
        const unsigned nn = __shfl_up(ni, off);
        const unsigned ff = __shfl_up(fi, off);
        if (lane >= off) { ni += nn; fi += ff; }
    }
    const unsigned gts = __shfl(fi, 63);       // total fg for this class

    unsigned Tc = ni - nl;                     // exclusive prefixes
    unsigned Fc = fi - fl;

    double Jprev;
    {
        const unsigned den = gts + Tc - Fc;
        Jprev = den ? 1.0 - (double)(gts - Fc) / (double)den : 0.0;
    }
    double loss = 0.0;
    #pragma unroll
    for (int k = 0; k < PER; ++k) {
        if (n[k]) {
            Tc += n[k]; Fc += f[k];
            const unsigned den = gts + Tc - Fc;
            const double J = den ? 1.0 - (double)(gts - Fc) / (double)den : 0.0;
            const int s = lane * PER + k;
            const double center = ((double)(NBINS - 1 - s) + 0.5) / (double)NBINS;
            loss += center * (J - Jprev);
            Jprev = J;
        }
    }

    // wave reduction
    for (int off = 32; off > 0; off >>= 1) loss += __shfl_down(loss, off);
    if (lane == 0) atomicAdd(out, (float)loss);
}

extern "C" void kernel_launch(void* const* d_in, const int* in_sizes, int n_in,
                              void* d_out, int out_size, void* d_ws, size_t ws_size,
                              hipStream_t stream) {
    const float* logits = (const float*)d_in[0];
    const int*   label  = (const int*)d_in[1];
    unsigned long long* g_hist = (unsigned long long*)d_ws;

    hipMemsetAsync(d_ws, 0, (size_t)C_CLS * NBINS * sizeof(unsigned long long), stream);
    hipMemsetAsync(d_out, 0, sizeof(float), stream);

    // 1024 blocks x 256 thr: 4 blocks/CU (LDS 38.9KB), 4 pair-iters/thread exactly
    lovasz_hist<<<1024, 256, 0, stream>>>(logits, label, g_hist);
    lovasz_finalize<<<C_CLS, 64, 0, stream>>>(g_hist, (float*)d_out);
}

// Round 2
// 58.575 us; speedup vs baseline: 1.8767x; 1.8767x over previous
//
#include <hip/hip_runtime.h>

#define C_CLS 19
#define NBINS 128
#define NREP 4
#define ROWSTRIDE (NBINS * NREP + 1)   // 513 words per class row (odd -> bank rotate)
#define HW_SHIFT 19                    // H*W = 512*1024 = 2^19
#define HW (1 << HW_SHIFT)
#define NPIX (4 * HW)                  // B=4
#define IGNORE_LAB 255

// ---------------------------------------------------------------------------
// Kernel 1: softmax + per-(class,bin) histogram of err = |fg - p_c|.
// 4 replica sub-histograms (lane&3) at consecutive words -> colliding lanes
// RMW different banks in parallel. Entry packs (count<<16)|fg_count.
// Flush: one u64 global atomic per nonempty entry: (count<<32)|fg.
// ---------------------------------------------------------------------------
__global__ __launch_bounds__(512) void lovasz_hist(
    const float* __restrict__ logits, const int* __restrict__ label,
    unsigned long long* __restrict__ g_hist)
{
    __shared__ unsigned hist[C_CLS * ROWSTRIDE];
    for (int i = threadIdx.x; i < C_CLS * ROWSTRIDE; i += blockDim.x) hist[i] = 0u;
    __syncthreads();

    const int rep = threadIdx.x & (NREP - 1);
    const int npairs = NPIX / 2;
    const int stride = gridDim.x * blockDim.x;
    for (int pr = blockIdx.x * blockDim.x + threadIdx.x; pr < npairs; pr += stride) {
        const long long p = (long long)pr * 2;
        const int b  = (int)(p >> HW_SHIFT);
        const int hw = (int)(p & (HW - 1));
        const float* base = logits + ((long long)b * C_CLS << HW_SHIFT) + hw;

        float2 e[C_CLS];
        float mx = -3.0e38f, my = -3.0e38f;
        #pragma unroll
        for (int c = 0; c < C_CLS; ++c) {
            float2 v = *(const float2*)(base + ((long long)c << HW_SHIFT));
            e[c] = v;
            mx = fmaxf(mx, v.x);
            my = fmaxf(my, v.y);
        }
        float sx = 0.f, sy = 0.f;
        #pragma unroll
        for (int c = 0; c < C_CLS; ++c) {
            float ex = __expf(e[c].x - mx);
            float ey = __expf(e[c].y - my);
            e[c].x = ex; e[c].y = ey;
            sx += ex; sy += ey;
        }
        const float rx = 1.f / sx, ry = 1.f / sy;

        const int2 lab = *(const int2*)(label + p);
        const bool v0 = (lab.x != IGNORE_LAB);
        const bool v1 = (lab.y != IGNORE_LAB);

        #pragma unroll
        for (int c = 0; c < C_CLS; ++c) {
            const int rowbase = c * ROWSTRIDE + rep;
            if (v0) {
                const float pc = e[c].x * rx;
                const unsigned fg = (lab.x == c) ? 1u : 0u;
                const float err = fg ? (1.f - pc) : pc;
                int bin = (int)(err * (float)NBINS);
                bin = bin > (NBINS - 1) ? (NBINS - 1) : bin;
                atomicAdd(&hist[rowbase + (bin << 2)], 0x10000u + fg);
            }
            if (v1) {
                const float pc = e[c].y * ry;
                const unsigned fg = (lab.y == c) ? 1u : 0u;
                const float err = fg ? (1.f - pc) : pc;
                int bin = (int)(err * (float)NBINS);
                bin = bin > (NBINS - 1) ? (NBINS - 1) : bin;
                atomicAdd(&hist[rowbase + (bin << 2)], 0x10000u + fg);
            }
        }
    }
    __syncthreads();

    // Flush: sum 4 replicas (packed-safe: fg<=8192/entry, count<=8192/entry)
    for (int e = threadIdx.x; e < C_CLS * NBINS; e += blockDim.x) {
        const int c = e >> 7;           // /128
        const int b = e & (NBINS - 1);
        const int base = c * ROWSTRIDE + (b << 2);
        const unsigned v = hist[base] + hist[base + 1] + hist[base + 2] + hist[base + 3];
        if (v) {
            const unsigned long long add =
                ((unsigned long long)(v >> 16) << 32) | (unsigned long long)(v & 0xFFFFu);
            atomicAdd(&g_hist[e], add);
        }
    }
}

// ---------------------------------------------------------------------------
// Kernel 2: per class (one wave each), scan bins in DESCENDING err order.
// jacc(T,F) = 1 - (gts-F)/(gts+T-F) at exact integer boundaries (fp64).
// loss += bin_center * (jacc_after - jacc_before); atomicAdd into out.
// ---------------------------------------------------------------------------
__global__ __launch_bounds__(64) void lovasz_finalize(
    const unsigned long long* __restrict__ g_hist, float* __restrict__ out)
{
    const int c = blockIdx.x;          // class
    const int lane = threadIdx.x;      // 0..63
    const int PER = NBINS / 64;        // 2 bins per lane

    unsigned n[PER], f[PER];
    unsigned nl = 0, fl = 0;
    #pragma unroll
    for (int k = 0; k < PER; ++k) {
        const int s = lane * PER + k;          // sequence position (desc err)
        const int bin = NBINS - 1 - s;
        const unsigned long long h = g_hist[c * NBINS + bin];
        n[k] = (unsigned)(h >> 32);
        f[k] = (unsigned)(h & 0xFFFFFFFFull);
        nl += n[k]; fl += f[k];
    }

    // inclusive wave scan over lanes
    unsigned ni = nl, fi = fl;
    for (int off = 1; off < 64; off <<= 1) {
        const unsigned nn = __shfl_up(ni, off);
        const unsigned ff = __shfl_up(fi, off);
        if (lane >= off) { ni += nn; fi += ff; }
    }
    const unsigned gts = __shfl(fi, 63);       // total fg for this class

    unsigned Tc = ni - nl;                     // exclusive prefixes
    unsigned Fc = fi - fl;

    double Jprev;
    {
        const unsigned den = gts + Tc - Fc;
        Jprev = den ? 1.0 - (double)(gts - Fc) / (double)den : 0.0;
    }
    double loss = 0.0;
    #pragma unroll
    for (int k = 0; k < PER; ++k) {
        if (n[k]) {
            Tc += n[k]; Fc += f[k];
            const unsigned den = gts + Tc - Fc;
            const double J = den ? 1.0 - (double)(gts - Fc) / (double)den : 0.0;
            const int s = lane * PER + k;
            const double center = ((double)(NBINS - 1 - s) + 0.5) / (double)NBINS;
            loss += center * (J - Jprev);
            Jprev = J;
        }
    }

    // wave reduction
    for (int off = 32; off > 0; off >>= 1) loss += __shfl_down(loss, off);
    if (lane == 0) atomicAdd(out, (float)loss);
}

extern "C" void kernel_launch(void* const* d_in, const int* in_sizes, int n_in,
                              void* d_out, int out_size, void* d_ws, size_t ws_size,
                              hipStream_t stream) {
    const float* logits = (const float*)d_in[0];
    const int*   label  = (const int*)d_in[1];
    unsigned long long* g_hist = (unsigned long long*)d_ws;

    hipMemsetAsync(d_ws, 0, (size_t)C_CLS * NBINS * sizeof(unsigned long long), stream);
    hipMemsetAsync(d_out, 0, sizeof(float), stream);

    // 1024 blocks x 512 thr: 4 blocks/CU (LDS 39KB) = 32 waves/CU; 4 pair-iters/thread
    lovasz_hist<<<1024, 512, 0, stream>>>(logits, label, g_hist);
    lovasz_finalize<<<C_CLS, 64, 0, stream>>>(g_hist, (float*)d_out);
}

// Round 3
// 54.226 us; speedup vs baseline: 2.0272x; 1.0802x over previous
//
#include <hip/hip_runtime.h>

#define C_CLS 19
#define NBINS 128
#define NREP 8
#define ROWSTRIDE (NBINS * NREP + 1)   // 1025 words per class row (odd -> bank rotate)
#define HW_SHIFT 19                    // H*W = 512*1024 = 2^19
#define HW (1 << HW_SHIFT)
#define NPIX (4 * HW)                  // B=4
#define IGNORE_LAB 255

// ---------------------------------------------------------------------------
// Kernel 1: softmax + per-(class,bin) histogram of err = |fg - p_c|.
// 8 replica sub-histograms (lane&7) at consecutive words -> hot-bin lanes
// RMW different banks in parallel. Entry packs (count<<16)|fg_count.
// LDS 77.9KB -> 2 blocks/CU (16 waves/CU). Flush: one u64 global atomic
// per nonempty entry: (count<<32)|fg.
// ---------------------------------------------------------------------------
__global__ __launch_bounds__(512) void lovasz_hist(
    const float* __restrict__ logits, const int* __restrict__ label,
    unsigned long long* __restrict__ g_hist)
{
    __shared__ unsigned hist[C_CLS * ROWSTRIDE];
    for (int i = threadIdx.x; i < C_CLS * ROWSTRIDE; i += blockDim.x) hist[i] = 0u;
    __syncthreads();

    const int rep = threadIdx.x & (NREP - 1);
    const int npairs = NPIX / 2;
    const int stride = gridDim.x * blockDim.x;   // 512*512 = 262144 -> 8 iters
    for (int pr = blockIdx.x * blockDim.x + threadIdx.x; pr < npairs; pr += stride) {
        const long long p = (long long)pr * 2;
        const int b  = (int)(p >> HW_SHIFT);
        const int hw = (int)(p & (HW - 1));
        const float* base = logits + ((long long)b * C_CLS << HW_SHIFT) + hw;

        float2 e[C_CLS];
        float mx = -3.0e38f, my = -3.0e38f;
        #pragma unroll
        for (int c = 0; c < C_CLS; ++c) {
            float2 v = *(const float2*)(base + ((long long)c << HW_SHIFT));
            e[c] = v;
            mx = fmaxf(mx, v.x);
            my = fmaxf(my, v.y);
        }
        float sx = 0.f, sy = 0.f;
        #pragma unroll
        for (int c = 0; c < C_CLS; ++c) {
            float ex = __expf(e[c].x - mx);
            float ey = __expf(e[c].y - my);
            e[c].x = ex; e[c].y = ey;
            sx += ex; sy += ey;
        }
        const float rx = 1.f / sx, ry = 1.f / sy;

        const int2 lab = *(const int2*)(label + p);
        const bool v0 = (lab.x != IGNORE_LAB);
        const bool v1 = (lab.y != IGNORE_LAB);

        #pragma unroll
        for (int c = 0; c < C_CLS; ++c) {
            const int rowbase = c * ROWSTRIDE + rep;
            if (v0) {
                const float pc = e[c].x * rx;
                const unsigned fg = (lab.x == c) ? 1u : 0u;
                const float err = fg ? (1.f - pc) : pc;
                int bin = (int)(err * (float)NBINS);
                bin = bin > (NBINS - 1) ? (NBINS - 1) : bin;
                atomicAdd(&hist[rowbase + (bin << 3)], 0x10000u + fg);
            }
            if (v1) {
                const float pc = e[c].y * ry;
                const unsigned fg = (lab.y == c) ? 1u : 0u;
                const float err = fg ? (1.f - pc) : pc;
                int bin = (int)(err * (float)NBINS);
                bin = bin > (NBINS - 1) ? (NBINS - 1) : bin;
                atomicAdd(&hist[rowbase + (bin << 3)], 0x10000u + fg);
            }
        }
    }
    __syncthreads();

    // Flush: sum 8 replicas (packed-safe: count<=8192 pix/block, fg<=count)
    for (int e = threadIdx.x; e < C_CLS * NBINS; e += blockDim.x) {
        const int c = e >> 7;           // /128
        const int b = e & (NBINS - 1);
        const int base = c * ROWSTRIDE + (b << 3);
        unsigned v = 0;
        #pragma unroll
        for (int r = 0; r < NREP; ++r) v += hist[base + r];
        if (v) {
            const unsigned long long add =
                ((unsigned long long)(v >> 16) << 32) | (unsigned long long)(v & 0xFFFFu);
            atomicAdd(&g_hist[e], add);
        }
    }
}

// ---------------------------------------------------------------------------
// Kernel 2: per class (one wave each), scan bins in DESCENDING err order.
// jacc(T,F) = 1 - (gts-F)/(gts+T-F) at exact integer boundaries (fp64).
// loss += bin_center * (jacc_after - jacc_before); atomicAdd into out.
// ---------------------------------------------------------------------------
__global__ __launch_bounds__(64) void lovasz_finalize(
    const unsigned long long* __restrict__ g_hist, float* __restrict__ out)
{
    const int c = blockIdx.x;          // class
    const int lane = threadIdx.x;      // 0..63
    const int PER = NBINS / 64;        // 2 bins per lane

    unsigned n[PER], f[PER];
    unsigned nl = 0, fl = 0;
    #pragma unroll
    for (int k = 0; k < PER; ++k) {
        const int s = lane * PER + k;          // sequence position (desc err)
        const int bin = NBINS - 1 - s;
        const unsigned long long h = g_hist[c * NBINS + bin];
        n[k] = (unsigned)(h >> 32);
        f[k] = (unsigned)(h & 0xFFFFFFFFull);
        nl += n[k]; fl += f[k];
    }

    // inclusive wave scan over lanes
    unsigned ni = nl, fi = fl;
    for (int off = 1; off < 64; off <<= 1) {
        const unsigned nn = __shfl_up(ni, off);
        const unsigned ff = __shfl_up(fi, off);
        if (lane >= off) { ni += nn; fi += ff; }
    }
    const unsigned gts = __shfl(fi, 63);       // total fg for this class

    unsigned Tc = ni - nl;                     // exclusive prefixes
    unsigned Fc = fi - fl;

    double Jprev;
    {
        const unsigned den = gts + Tc - Fc;
        Jprev = den ? 1.0 - (double)(gts - Fc) / (double)den : 0.0;
    }
    double loss = 0.0;
    #pragma unroll
    for (int k = 0; k < PER; ++k) {
        if (n[k]) {
            Tc += n[k]; Fc += f[k];
            const unsigned den = gts + Tc - Fc;
            const double J = den ? 1.0 - (double)(gts - Fc) / (double)den : 0.0;
            const int s = lane * PER + k;
            const double center = ((double)(NBINS - 1 - s) + 0.5) / (double)NBINS;
            loss += center * (J - Jprev);
            Jprev = J;
        }
    }

    // wave reduction
    for (int off = 32; off > 0; off >>= 1) loss += __shfl_down(loss, off);
    if (lane == 0) atomicAdd(out, (float)loss);
}

extern "C" void kernel_launch(void* const* d_in, const int* in_sizes, int n_in,
                              void* d_out, int out_size, void* d_ws, size_t ws_size,
                              hipStream_t stream) {
    const float* logits = (const float*)d_in[0];
    const int*   label  = (const int*)d_in[1];
    unsigned long long* g_hist = (unsigned long long*)d_ws;

    hipMemsetAsync(d_ws, 0, (size_t)C_CLS * NBINS * sizeof(unsigned long long), stream);
    hipMemsetAsync(d_out, 0, sizeof(float), stream);

    // 512 blocks x 512 thr: 2 blocks/CU (LDS 78KB) = 16 waves/CU; 8 pair-iters/thread
    lovasz_hist<<<512, 512, 0, stream>>>(logits, label, g_hist);
    lovasz_finalize<<<C_CLS, 64, 0, stream>>>(g_hist, (float*)d_out);
}